// Round 1
// baseline (686.910 us; speedup 1.0000x reference)
//
#include <hip/hip_runtime.h>

typedef __attribute__((ext_vector_type(2))) float f32x2;
typedef __attribute__((ext_vector_type(4))) float f32x4;
typedef __attribute__((ext_vector_type(16))) float f32x16;
typedef __attribute__((ext_vector_type(8))) short bf16x8;
typedef __attribute__((ext_vector_type(8))) unsigned short u16x8;

#define GL2LDS(g, l) __builtin_amdgcn_global_load_lds( \
    (const __attribute__((address_space(1))) void*)(g), \
    (__attribute__((address_space(3))) void*)(l), 16, 0, 0)

__device__ __forceinline__ unsigned short f2bf(float x) {
    union { float f; unsigned u; } v; v.f = x;
    unsigned r = (v.u + 0x7FFF + ((v.u >> 16) & 1)) >> 16;
    return (unsigned short)r;
}

// ---------------- Kernel 1 (fused): blocks [0,640): Wc masked expert-sum;
// blocks [640, 17024): x fp32 -> bf16 conversion. The two are independent.
__global__ __launch_bounds__(256) void k_prep(const float* __restrict__ c0,
                                              const float* __restrict__ c1,
                                              const int* __restrict__ m0,
                                              const int* __restrict__ m1,
                                              float* __restrict__ Wc,
                                              const float* __restrict__ x,
                                              unsigned short* __restrict__ xb) {
    int b = blockIdx.x;
    if (b < 640) {
        int idx = b * 256 + threadIdx.x;
        if (idx >= 4096 * 40) return;
        int o = idx / 40, c = idx % 40;
        float s = 0.f;
        if (c < 32) {
            #pragma unroll
            for (int e = 0; e < 3; ++e) {
                int i = (e * 4096 + o) * 32 + c;
                s += c0[i] * (m0[i] != 0 ? 1.f : 0.f);
            }
        } else {
            int r = c - 32;
            #pragma unroll
            for (int e = 0; e < 3; ++e) {
                int i = (e * 4096 + o) * 8 + r;
                s += c1[i] * (m1[i] != 0 ? 1.f : 0.f);
            }
        }
        Wc[idx] = s;
    } else {
        int idx = (b - 640) * 256 + threadIdx.x;  // one per 8 elements; 4194304 total
        f32x4 f0 = ((const f32x4*)x)[(size_t)idx * 2];
        f32x4 f1 = ((const f32x4*)x)[(size_t)idx * 2 + 1];
        u16x8 o;
        o[0] = f2bf(f0[0]); o[1] = f2bf(f0[1]); o[2] = f2bf(f0[2]); o[3] = f2bf(f0[3]);
        o[4] = f2bf(f1[0]); o[5] = f2bf(f1[1]); o[6] = f2bf(f1[2]); o[7] = f2bf(f1[3]);
        *(u16x8*)(xb + (size_t)idx * 8) = o;
    }
}

// ---------------- Kernel 2: G[t][40] = 0.5 * (F @ Wc)[t][:]
// Block: 8 t-values, 256 threads = 32 f_slots x 2 t-groups(4t) x 4 r-groups(10r).
// 512 blocks -> 2 blocks/CU (was 1) for latency hiding.
__global__ __launch_bounds__(256) void k_gmat(const float* __restrict__ Wc,
                                              float* __restrict__ G) {
    __shared__ float lds[10752];  // staging: 128 f-rows x 84 floats; reused for reduction
    int tid = threadIdx.x;
    int t_base = blockIdx.x * 8;
    int f_slot = tid & 31;
    int tg = (tid >> 5) & 1;
    int rg = tid >> 6;
    float acc[4][10];
    #pragma unroll
    for (int a = 0; a < 4; ++a)
        #pragma unroll
        for (int b = 0; b < 10; ++b) acc[a][b] = 0.f;

    for (int ch = 0; ch < 16; ++ch) {
        __syncthreads();
        // stage 128 f-rows: row f_local <- Wc[(2f-1)*40 .. +80) (cos row || sin row)
        #pragma unroll
        for (int j = 0; j < 10; ++j) {
            int idx = tid + j * 256;        // 0..2559 float4 slots
            int row = idx / 20;
            int v = idx % 20;
            int f = ch * 128 + row;
            f32x4 val = {0.f, 0.f, 0.f, 0.f};
            if (f >= 1) val = *(const f32x4*)(Wc + (2 * f - 1) * 40 + v * 4);
            *(f32x4*)(lds + row * 84 + v * 4) = val;
        }
        __syncthreads();
        #pragma unroll
        for (int j2 = 0; j2 < 4; ++j2) {
            int f_local = f_slot + 32 * j2;
            int f = ch * 128 + f_local;
            float cs[4], sn[4];
            #pragma unroll
            for (int tt = 0; tt < 4; ++tt) {
                int t = t_base + tg * 4 + tt;
                int ph = (f * t) & 4095;                    // exact phase mod 2pi
                float rev = (float)ph * (1.0f / 4096.0f);   // revolutions, exact
                cs[tt] = __builtin_amdgcn_cosf(rev);        // cos(2*pi*rev)
                sn[tt] = __builtin_amdgcn_sinf(rev);
            }
            const float* Lc = lds + f_local * 84 + rg * 10;
            const float* Ls = Lc + 40;
            #pragma unroll
            for (int rr = 0; rr < 10; ++rr) {
                float wc = Lc[rr], ws = Ls[rr];
                #pragma unroll
                for (int tt = 0; tt < 4; ++tt)
                    acc[tt][rr] += cs[tt] * wc + sn[tt] * ws;
            }
        }
    }
    __syncthreads();
    #pragma unroll
    for (int tt = 0; tt < 4; ++tt)
        #pragma unroll
        for (int rr = 0; rr < 10; ++rr)
            lds[tid * 40 + tt * 10 + rr] = acc[tt][rr];
    __syncthreads();
    for (int oi = tid; oi < 320; oi += 256) {
        int t_local = oi / 40, rc = oi % 40;
        int tg2 = t_local >> 2, tsub = t_local & 3;
        int rg2 = rc / 10, rsub = rc % 10;
        float s = 0.f;
        #pragma unroll
        for (int fs = 0; fs < 32; ++fs)
            s += lds[(fs + tg2 * 32 + rg2 * 64) * 40 + tsub * 10 + rsub];
        int t = t_base + t_local;
        float dc = Wc[rc];
        float ny = Wc[4095 * 40 + rc];
        float sign = (t & 1) ? -1.f : 1.f;
        // y[t] = sqrt(2/n)*pairsum + (c0 + (-1)^t c_{n-1})/sqrt(n);  n=4096; x0.5 SCALING
        float g = 0.5f * (0.0220970869120796f * s + (dc + sign * ny) * (1.0f / 64.0f));
        G[t * 40 + rc] = g;
    }
}

// ---------------- Kernel 3: Wcomb[t][d] (bf16) = W_base[t][d] + sum_k G[t][k]*E[k][d]
// Tile: 32 t x 256 d per block. LDS reads as f32x2 at 8B lane stride: banks
// (dg*2)%32 -> 2 lanes/bank-pair + tg-broadcast = conflict-free (was 8-way on b128).
__global__ __launch_bounds__(256) void k_wcomb(const float* __restrict__ Wb,
                                               const float* __restrict__ enc0,
                                               const float* __restrict__ enc1,
                                               const float* __restrict__ G,
                                               unsigned short* __restrict__ Wcb) {
    __shared__ float ldsE[40 * 256];
    __shared__ float ldsG[32 * 40];
    int tid = threadIdx.x;
    int d0 = blockIdx.x * 256;
    int t0 = blockIdx.y * 32;
    #pragma unroll
    for (int j = 0; j < 10; ++j) {
        int idx = tid + j * 256;   // float4 slots, 40 rows x 64 slots
        int k = idx / 64, v = idx % 64;
        const float* src = (k < 32) ? (enc0 + (size_t)k * 4096) : (enc1 + (size_t)(k - 32) * 4096);
        *(f32x4*)(ldsE + k * 256 + v * 4) = *(const f32x4*)(src + d0 + v * 4);
    }
    #pragma unroll
    for (int j = 0; j < 5; ++j) {
        int idx = tid + j * 256;   // 0..1279
        ldsG[idx] = G[(size_t)(t0 + idx / 40) * 40 + (idx % 40)];
    }
    __syncthreads();
    int dg = tid & 31, tg = tid >> 5;
    // thread covers d-cols {s*64 + dg*2, +1} for s=0..3, t rows t0+tg*4..+3
    f32x2 a[4][4];  // [s][tt]
    #pragma unroll
    for (int s = 0; s < 4; ++s)
        #pragma unroll
        for (int tt = 0; tt < 4; ++tt) a[s][tt] = (f32x2){0.f, 0.f};
    #pragma unroll 8
    for (int r = 0; r < 40; ++r) {
        f32x2 e[4];
        #pragma unroll
        for (int s = 0; s < 4; ++s)
            e[s] = *(const f32x2*)(ldsE + r * 256 + s * 64 + dg * 2);
        #pragma unroll
        for (int tt = 0; tt < 4; ++tt) {
            float g = ldsG[(tg * 4 + tt) * 40 + r];
            #pragma unroll
            for (int s = 0; s < 4; ++s)
                a[s][tt] += g * e[s];
        }
    }
    #pragma unroll
    for (int tt = 0; tt < 4; ++tt) {
        int t = t0 + tg * 4 + tt;
        #pragma unroll
        for (int s = 0; s < 4; ++s) {
            int d = d0 + s * 64 + dg * 2;
            f32x2 wv = *(const f32x2*)(Wb + (size_t)t * 4096 + d);
            f32x2 rv = a[s][tt] + wv;
            unsigned short lo = f2bf(rv[0]), hi = f2bf(rv[1]);
            *(unsigned*)(Wcb + (size_t)t * 4096 + d) = (unsigned)lo | ((unsigned)hi << 16);
        }
    }
}

// ---------------- Kernel 4: C[8192][4096] = A[8192][4096] @ B[4096][4096]^T + bias
// 256x256 tile, BK=64, 8 waves (2Mx4N), 512 threads, 128 KiB LDS (2x dbuf A+B).
// Deep-pipelined 4-phase schedule (per K-tile), counted vmcnt (never 0 in steady
// state), raw s_barrier (NO __syncthreads: its vmcnt(0) drains the pipeline),
// setprio(1) around each MFMA cluster.
//   P0: read A-lo frags (8xb128) + B0 (4) | bar | 8 MFMA q00 | bar
//   P1: read A-hi (8)                     | bar | 8 MFMA q10 | bar
//   P2: read B1 (4)                       | bar | 8 MFMA q11 | bar
//   P3: stage tile t+2 into buf[t&1] (8 GL2LDS; buffer free: last read was P2)
//                                         | bar | 8 MFMA q01 | vmcnt(8)+bar
// vmcnt(8) at the boundary waits only for tile t+1's 8 loads (issued 4 phases
// earlier) while tile t+2's 8 stay in flight across the barrier.
// LDS layout as before: slot (row, cg) holds global (row, cg ^ (row&7)).
__global__ __launch_bounds__(512, 2) void k_gemm(const unsigned short* __restrict__ A,
                                                 const unsigned short* __restrict__ B,
                                                 const float* __restrict__ bias,
                                                 float* __restrict__ C) {
    __shared__ __align__(16) short As[2][256 * 64];   // 64 KiB
    __shared__ __align__(16) short Bs[2][256 * 64];   // 64 KiB
    const int tid = threadIdx.x;
    const int lane = tid & 63, w = tid >> 6;
    const int wm = w >> 2, wn = w & 3;          // 2 M-waves x 4 N-waves
    const int col = lane & 31, hi = lane >> 5;  // MFMA fragment lane decomposition
    const int sw = col & 7;                     // swizzle key (== row&7 for frag rows)

    // XCD-aware bijective swizzle: 512 blocks, 512 % 8 == 0
    int bid = blockIdx.x;
    int swz = (bid & 7) * 64 + (bid >> 3);
    int m0 = (swz >> 4) * 256;                  // 32 M-tiles
    int n0 = (swz & 15) * 256;                  // 16 N-tiles

    // staging geometry: one GL2LDS(512 threads) = 64 rows x 64 cols (8 KiB)
    // wave w writes rows w*8..w*8+8 of each 64-row chunk; lane -> (row=l>>3, cg=l&7),
    // global col-group pre-swizzled so LDS slot (row,c) holds global (row, c^(row&7)).
    const int srow = w * 8 + (lane >> 3);
    const int scg  = (lane & 7) ^ ((lane >> 3) & 7);
    const unsigned short* Ag = A + (size_t)(m0 + srow) * 4096 + scg * 8;
    const unsigned short* Bg = B + (size_t)(n0 + srow) * 4096 + scg * 8;

#define STAGE(buf, kt) do { \
    _Pragma("unroll") \
    for (int c = 0; c < 4; ++c) { \
        GL2LDS(Ag + (size_t)(c * 64) * 4096 + (kt), &As[buf][(c * 64 + w * 8) * 64]); \
        GL2LDS(Bg + (size_t)(c * 64) * 4096 + (kt), &Bs[buf][(c * 64 + w * 8) * 64]); \
    } \
} while (0)

    // fragment read offsets (shorts)
    int aoff[4], boff[2], co[4];
    #pragma unroll
    for (int mf = 0; mf < 4; ++mf) aoff[mf] = (wm * 128 + mf * 32 + col) * 64;
    #pragma unroll
    for (int nf = 0; nf < 2; ++nf) boff[nf] = (wn * 64 + nf * 32 + col) * 64;
    #pragma unroll
    for (int ks = 0; ks < 4; ++ks) co[ks] = ((ks * 2 + hi) ^ sw) * 8;

    f32x16 acc[4][2];
    #pragma unroll
    for (int mf = 0; mf < 4; ++mf)
        #pragma unroll
        for (int nf = 0; nf < 2; ++nf)
            #pragma unroll
            for (int r = 0; r < 16; ++r) acc[mf][nf][r] = 0.f;

    // prologue: 2-deep prefetch; vmcnt(8) -> tile0 complete, tile1 in flight
    STAGE(0, 0);
    STAGE(1, 64);
    asm volatile("s_waitcnt vmcnt(8)\n\ts_barrier" ::: "memory");

    for (int t = 0; t < 64; ++t) {
        const int cur = t & 1;
        // ---- P0: A-lo (mf 0,1) + B0; MFMA q00
        bf16x8 aLo[2][4], b0[4];
        #pragma unroll
        for (int ks = 0; ks < 4; ++ks) {
            aLo[0][ks] = *(const bf16x8*)&As[cur][aoff[0] + co[ks]];
            aLo[1][ks] = *(const bf16x8*)&As[cur][aoff[1] + co[ks]];
            b0[ks]     = *(const bf16x8*)&Bs[cur][boff[0] + co[ks]];
        }
        asm volatile("s_barrier" ::: "memory");
        __builtin_amdgcn_s_setprio(1);
        #pragma unroll
        for (int ks = 0; ks < 4; ++ks) {
            acc[0][0] = __builtin_amdgcn_mfma_f32_32x32x16_bf16(aLo[0][ks], b0[ks], acc[0][0], 0, 0, 0);
            acc[1][0] = __builtin_amdgcn_mfma_f32_32x32x16_bf16(aLo[1][ks], b0[ks], acc[1][0], 0, 0, 0);
        }
        __builtin_amdgcn_s_setprio(0);
        asm volatile("s_barrier" ::: "memory");
        // ---- P1: A-hi (mf 2,3); MFMA q10 (reuse B0)
        bf16x8 aHi[2][4];
        #pragma unroll
        for (int ks = 0; ks < 4; ++ks) {
            aHi[0][ks] = *(const bf16x8*)&As[cur][aoff[2] + co[ks]];
            aHi[1][ks] = *(const bf16x8*)&As[cur][aoff[3] + co[ks]];
        }
        asm volatile("s_barrier" ::: "memory");
        __builtin_amdgcn_s_setprio(1);
        #pragma unroll
        for (int ks = 0; ks < 4; ++ks) {
            acc[2][0] = __builtin_amdgcn_mfma_f32_32x32x16_bf16(aHi[0][ks], b0[ks], acc[2][0], 0, 0, 0);
            acc[3][0] = __builtin_amdgcn_mfma_f32_32x32x16_bf16(aHi[1][ks], b0[ks], acc[3][0], 0, 0, 0);
        }
        __builtin_amdgcn_s_setprio(0);
        asm volatile("s_barrier" ::: "memory");
        // ---- P2: B1; MFMA q11 (reuse A-hi)
        bf16x8 b1[4];
        #pragma unroll
        for (int ks = 0; ks < 4; ++ks)
            b1[ks] = *(const bf16x8*)&Bs[cur][boff[1] + co[ks]];
        asm volatile("s_barrier" ::: "memory");
        __builtin_amdgcn_s_setprio(1);
        #pragma unroll
        for (int ks = 0; ks < 4; ++ks) {
            acc[2][1] = __builtin_amdgcn_mfma_f32_32x32x16_bf16(aHi[0][ks], b1[ks], acc[2][1], 0, 0, 0);
            acc[3][1] = __builtin_amdgcn_mfma_f32_32x32x16_bf16(aHi[1][ks], b1[ks], acc[3][1], 0, 0, 0);
        }
        __builtin_amdgcn_s_setprio(0);
        asm volatile("s_barrier" ::: "memory");
        // ---- P3: stage tile t+2 into buf[cur] (its reads finished at P2); MFMA q01
        if (t + 2 < 64) STAGE(cur, (t + 2) * 64);
        asm volatile("s_barrier" ::: "memory");
        __builtin_amdgcn_s_setprio(1);
        #pragma unroll
        for (int ks = 0; ks < 4; ++ks) {
            acc[0][1] = __builtin_amdgcn_mfma_f32_32x32x16_bf16(aLo[0][ks], b1[ks], acc[0][1], 0, 0, 0);
            acc[1][1] = __builtin_amdgcn_mfma_f32_32x32x16_bf16(aLo[1][ks], b1[ks], acc[1][1], 0, 0, 0);
        }
        __builtin_amdgcn_s_setprio(0);
        if (t + 2 < 64) {
            asm volatile("s_waitcnt vmcnt(8)\n\ts_barrier" ::: "memory");  // t+1 ready; t+2 in flight
        } else if (t + 1 < 64) {
            asm volatile("s_waitcnt vmcnt(0)\n\ts_barrier" ::: "memory");  // final drain (once)
        } else {
            asm volatile("s_barrier" ::: "memory");
        }
    }
#undef STAGE

    // C/D layout (m74/m101): col = lane&31, row = (reg&3) + 8*(reg>>2) + 4*(lane>>5)
    #pragma unroll
    for (int nf = 0; nf < 2; ++nf) {
        float bv = bias[n0 + wn * 64 + nf * 32 + col];
        #pragma unroll
        for (int mf = 0; mf < 4; ++mf) {
            #pragma unroll
            for (int r = 0; r < 16; ++r) {
                int row = m0 + wm * 128 + mf * 32 + (r & 3) + 8 * (r >> 2) + 4 * hi;
                C[(size_t)row * 4096 + n0 + wn * 64 + nf * 32 + col] = acc[mf][nf][r] + bv;
            }
        }
    }
}

extern "C" void kernel_launch(void* const* d_in, const int* in_sizes, int n_in,
                              void* d_out, int out_size, void* d_ws, size_t ws_size,
                              hipStream_t stream) {
    const float* x   = (const float*)d_in[0];   // [4,2048,4096]
    const float* Wb  = (const float*)d_in[1];   // [4096,4096]
    const float* bb  = (const float*)d_in[2];   // [4096]
    const float* e0  = (const float*)d_in[3];   // [32,4096]
    const float* e1  = (const float*)d_in[4];   // [8,4096]
    const float* c0  = (const float*)d_in[5];   // [3,4096,32]
    const float* c1  = (const float*)d_in[6];   // [3,4096,8]
    const int*   m0  = (const int*)d_in[7];     // [3,4096,32] bool->int32
    const int*   m1  = (const int*)d_in[8];     // [3,4096,8]
    float* out = (float*)d_out;                 // [4,2048,4096]

    char* ws = (char*)d_ws;
    unsigned short* xb  = (unsigned short*)ws;              // 67108864 B
    float* Wc           = (float*)(ws + 67108864);          // 655360 B
    float* G            = (float*)(ws + 67764224);          // 655360 B
    unsigned short* Wcb = (unsigned short*)(ws + 68419584); // 33554432 B

    k_prep <<<17024, 256, 0, stream>>>(c0, c1, m0, m1, Wc, x, xb);
    k_gmat <<<512, 256, 0, stream>>>(Wc, G);
    k_wcomb<<<dim3(16, 128), 256, 0, stream>>>(Wb, e0, e1, G, Wcb);
    k_gemm <<<512, 512, 0, stream>>>(xb, Wcb, bb, out);
}

// Round 2
// 625.108 us; speedup vs baseline: 1.0989x; 1.0989x over previous
//
#include <hip/hip_runtime.h>

typedef __attribute__((ext_vector_type(2))) float f32x2;
typedef __attribute__((ext_vector_type(4))) float f32x4;
typedef __attribute__((ext_vector_type(16))) float f32x16;
typedef __attribute__((ext_vector_type(8))) short bf16x8;
typedef __attribute__((ext_vector_type(8))) unsigned short u16x8;

#define GL2LDS(g, l) __builtin_amdgcn_global_load_lds( \
    (const __attribute__((address_space(1))) void*)(g), \
    (__attribute__((address_space(3))) void*)(l), 16, 0, 0)

__device__ __forceinline__ unsigned short f2bf(float x) {
    union { float f; unsigned u; } v; v.f = x;
    unsigned r = (v.u + 0x7FFF + ((v.u >> 16) & 1)) >> 16;
    return (unsigned short)r;
}

// ---------------- Kernel 1 (fused): blocks [0,640): Wc masked expert-sum;
// blocks [640, 17024): x fp32 -> bf16 conversion. The two are independent.
__global__ __launch_bounds__(256) void k_prep(const float* __restrict__ c0,
                                              const float* __restrict__ c1,
                                              const int* __restrict__ m0,
                                              const int* __restrict__ m1,
                                              float* __restrict__ Wc,
                                              const float* __restrict__ x,
                                              unsigned short* __restrict__ xb) {
    int b = blockIdx.x;
    if (b < 640) {
        int idx = b * 256 + threadIdx.x;
        if (idx >= 4096 * 40) return;
        int o = idx / 40, c = idx % 40;
        float s = 0.f;
        if (c < 32) {
            #pragma unroll
            for (int e = 0; e < 3; ++e) {
                int i = (e * 4096 + o) * 32 + c;
                s += c0[i] * (m0[i] != 0 ? 1.f : 0.f);
            }
        } else {
            int r = c - 32;
            #pragma unroll
            for (int e = 0; e < 3; ++e) {
                int i = (e * 4096 + o) * 8 + r;
                s += c1[i] * (m1[i] != 0 ? 1.f : 0.f);
            }
        }
        Wc[idx] = s;
    } else {
        int idx = (b - 640) * 256 + threadIdx.x;  // one per 8 elements; 4194304 total
        f32x4 f0 = ((const f32x4*)x)[(size_t)idx * 2];
        f32x4 f1 = ((const f32x4*)x)[(size_t)idx * 2 + 1];
        u16x8 o;
        o[0] = f2bf(f0[0]); o[1] = f2bf(f0[1]); o[2] = f2bf(f0[2]); o[3] = f2bf(f0[3]);
        o[4] = f2bf(f1[0]); o[5] = f2bf(f1[1]); o[6] = f2bf(f1[2]); o[7] = f2bf(f1[3]);
        *(u16x8*)(xb + (size_t)idx * 8) = o;
    }
}

// ---------------- Kernel 2: G[t][40] = 0.5 * (F @ Wc)[t][:]
__global__ __launch_bounds__(256) void k_gmat(const float* __restrict__ Wc,
                                              float* __restrict__ G) {
    __shared__ float lds[10752];  // staging: 128 f-rows x 84 floats; reused for reduction
    int tid = threadIdx.x;
    int t_base = blockIdx.x * 8;
    int f_slot = tid & 31;
    int tg = (tid >> 5) & 1;
    int rg = tid >> 6;
    float acc[4][10];
    #pragma unroll
    for (int a = 0; a < 4; ++a)
        #pragma unroll
        for (int b = 0; b < 10; ++b) acc[a][b] = 0.f;

    for (int ch = 0; ch < 16; ++ch) {
        __syncthreads();
        // stage 128 f-rows: row f_local <- Wc[(2f-1)*40 .. +80) (cos row || sin row)
        #pragma unroll
        for (int j = 0; j < 10; ++j) {
            int idx = tid + j * 256;        // 0..2559 float4 slots
            int row = idx / 20;
            int v = idx % 20;
            int f = ch * 128 + row;
            f32x4 val = {0.f, 0.f, 0.f, 0.f};
            if (f >= 1) val = *(const f32x4*)(Wc + (2 * f - 1) * 40 + v * 4);
            *(f32x4*)(lds + row * 84 + v * 4) = val;
        }
        __syncthreads();
        #pragma unroll
        for (int j2 = 0; j2 < 4; ++j2) {
            int f_local = f_slot + 32 * j2;
            int f = ch * 128 + f_local;
            float cs[4], sn[4];
            #pragma unroll
            for (int tt = 0; tt < 4; ++tt) {
                int t = t_base + tg * 4 + tt;
                int ph = (f * t) & 4095;                    // exact phase mod 2pi
                float rev = (float)ph * (1.0f / 4096.0f);   // revolutions, exact
                cs[tt] = __builtin_amdgcn_cosf(rev);        // cos(2*pi*rev)
                sn[tt] = __builtin_amdgcn_sinf(rev);
            }
            const float* Lc = lds + f_local * 84 + rg * 10;
            const float* Ls = Lc + 40;
            #pragma unroll
            for (int rr = 0; rr < 10; ++rr) {
                float wc = Lc[rr], ws = Ls[rr];
                #pragma unroll
                for (int tt = 0; tt < 4; ++tt)
                    acc[tt][rr] += cs[tt] * wc + sn[tt] * ws;
            }
        }
    }
    __syncthreads();
    #pragma unroll
    for (int tt = 0; tt < 4; ++tt)
        #pragma unroll
        for (int rr = 0; rr < 10; ++rr)
            lds[tid * 40 + tt * 10 + rr] = acc[tt][rr];
    __syncthreads();
    for (int oi = tid; oi < 320; oi += 256) {
        int t_local = oi / 40, rc = oi % 40;
        int tg2 = t_local >> 2, tsub = t_local & 3;
        int rg2 = rc / 10, rsub = rc % 10;
        float s = 0.f;
        #pragma unroll
        for (int fs = 0; fs < 32; ++fs)
            s += lds[(fs + tg2 * 32 + rg2 * 64) * 40 + tsub * 10 + rsub];
        int t = t_base + t_local;
        float dc = Wc[rc];
        float ny = Wc[4095 * 40 + rc];
        float sign = (t & 1) ? -1.f : 1.f;
        // y[t] = sqrt(2/n)*pairsum + (c0 + (-1)^t c_{n-1})/sqrt(n);  n=4096; x0.5 SCALING
        float g = 0.5f * (0.0220970869120796f * s + (dc + sign * ny) * (1.0f / 64.0f));
        G[t * 40 + rc] = g;
    }
}

// ---------------- Kernel 3: Wcomb[t][d] (bf16) = W_base[t][d] + sum_k G[t][k]*E[k][d]
__global__ __launch_bounds__(256) void k_wcomb(const float* __restrict__ Wb,
                                               const float* __restrict__ enc0,
                                               const float* __restrict__ enc1,
                                               const float* __restrict__ G,
                                               unsigned short* __restrict__ Wcb) {
    __shared__ float ldsE[40 * 256];
    __shared__ float ldsG[32 * 40];
    int tid = threadIdx.x;
    int d0 = blockIdx.x * 256;
    int t0 = blockIdx.y * 32;
    #pragma unroll
    for (int j = 0; j < 10; ++j) {
        int idx = tid + j * 256;   // float4 slots, 40 rows x 64 slots
        int k = idx / 64, v = idx % 64;
        const float* src = (k < 32) ? (enc0 + (size_t)k * 4096) : (enc1 + (size_t)(k - 32) * 4096);
        *(f32x4*)(ldsE + k * 256 + v * 4) = *(const f32x4*)(src + d0 + v * 4);
    }
    #pragma unroll
    for (int j = 0; j < 5; ++j) {
        int idx = tid + j * 256;   // 0..1279
        ldsG[idx] = G[(size_t)(t0 + idx / 40) * 40 + (idx % 40)];
    }
    __syncthreads();
    int dg = tid & 31, tg = tid >> 5;
    // thread covers d-cols {s*64 + dg*2, +1} for s=0..3, t rows t0+tg*4..+3
    f32x2 a[4][4];  // [s][tt]
    #pragma unroll
    for (int s = 0; s < 4; ++s)
        #pragma unroll
        for (int tt = 0; tt < 4; ++tt) a[s][tt] = (f32x2){0.f, 0.f};
    #pragma unroll 8
    for (int r = 0; r < 40; ++r) {
        f32x2 e[4];
        #pragma unroll
        for (int s = 0; s < 4; ++s)
            e[s] = *(const f32x2*)(ldsE + r * 256 + s * 64 + dg * 2);
        #pragma unroll
        for (int tt = 0; tt < 4; ++tt) {
            float g = ldsG[(tg * 4 + tt) * 40 + r];
            #pragma unroll
            for (int s = 0; s < 4; ++s)
                a[s][tt] += g * e[s];
        }
    }
    #pragma unroll
    for (int tt = 0; tt < 4; ++tt) {
        int t = t0 + tg * 4 + tt;
        #pragma unroll
        for (int s = 0; s < 4; ++s) {
            int d = d0 + s * 64 + dg * 2;
            f32x2 wv = *(const f32x2*)(Wb + (size_t)t * 4096 + d);
            f32x2 rv = a[s][tt] + wv;
            unsigned short lo = f2bf(rv[0]), hi = f2bf(rv[1]);
            *(unsigned*)(Wcb + (size_t)t * 4096 + d) = (unsigned)lo | ((unsigned)hi << 16);
        }
    }
}

// ---------------- Kernel 4: C[8192][4096] = A[8192][4096] @ B[4096][4096]^T + bias
// 256x256 tile, BK=64, 8 waves (2Mx4N), 512 threads, 128 KiB LDS (2x dbuf A+B).
// ONE barrier per K-tile (R1 post-mortem: the 8 lockstep barriers/tile were the
// regression). Per tile: read q00 frags -> MFMA q00 -> issue STAGE(t+1) into the
// OTHER buffer (T14 issue-early: ~1500 cy of MFMA ahead hides the load latency)
// -> remaining reads/MFMAs -> vmcnt(0) (near-free, loads long in flight) + s_barrier.
// Loop unrolled x2 so buffer indices are compile-time constants: the compiler can
// statically disambiguate As[0] reads vs As[1] GL2LDS writes (no conservative drain).
// LDS layout: slot (row, cg) holds global (row, cg ^ (row&7)); reads are
// (near-)conflict-free -- SQ_LDS_BANK_CONFLICT is dominated by GL2LDS write
// bursts (R1: counter == #GL2LDS x 8 exactly), not by these reads.
__global__ __launch_bounds__(512, 2) void k_gemm(const unsigned short* __restrict__ A,
                                                 const unsigned short* __restrict__ B,
                                                 const float* __restrict__ bias,
                                                 float* __restrict__ C) {
    __shared__ __align__(16) short As[2][256 * 64];   // 64 KiB
    __shared__ __align__(16) short Bs[2][256 * 64];   // 64 KiB
    const int tid = threadIdx.x;
    const int lane = tid & 63, w = tid >> 6;
    const int wm = w >> 2, wn = w & 3;          // 2 M-waves x 4 N-waves
    const int col = lane & 31, hi = lane >> 5;  // MFMA fragment lane decomposition
    const int sw = col & 7;                     // swizzle key (== row&7 for frag rows)

    // XCD-aware bijective swizzle: 512 blocks, 512 % 8 == 0
    int bid = blockIdx.x;
    int swz = (bid & 7) * 64 + (bid >> 3);
    int m0 = (swz >> 4) * 256;                  // 32 M-tiles
    int n0 = (swz & 15) * 256;                  // 16 N-tiles

    // staging geometry: one GL2LDS(512 threads) = 64 rows x 64 cols (8 KiB)
    const int srow = w * 8 + (lane >> 3);
    const int scg  = (lane & 7) ^ ((lane >> 3) & 7);
    const unsigned short* Ag = A + (size_t)(m0 + srow) * 4096 + scg * 8;
    const unsigned short* Bg = B + (size_t)(n0 + srow) * 4096 + scg * 8;

#define STAGE(buf, kt) do { \
    _Pragma("unroll") \
    for (int c = 0; c < 4; ++c) { \
        GL2LDS(Ag + (size_t)(c * 64) * 4096 + (kt), &As[buf][(c * 64 + w * 8) * 64]); \
        GL2LDS(Bg + (size_t)(c * 64) * 4096 + (kt), &Bs[buf][(c * 64 + w * 8) * 64]); \
    } \
} while (0)

    // fragment read offsets (shorts)
    int aoff[4], boff[2], co[4];
    #pragma unroll
    for (int mf = 0; mf < 4; ++mf) aoff[mf] = (wm * 128 + mf * 32 + col) * 64;
    #pragma unroll
    for (int nf = 0; nf < 2; ++nf) boff[nf] = (wn * 64 + nf * 32 + col) * 64;
    #pragma unroll
    for (int ks = 0; ks < 4; ++ks) co[ks] = ((ks * 2 + hi) ^ sw) * 8;

    f32x16 acc[4][2];
    #pragma unroll
    for (int mf = 0; mf < 4; ++mf)
        #pragma unroll
        for (int nf = 0; nf < 2; ++nf)
            #pragma unroll
            for (int r = 0; r < 16; ++r) acc[mf][nf][r] = 0.f;

// One K-tile: compute buf CB, stage tile at k=(kt)+64 into buf NB (if DO_STAGE).
// Program order: q00 reads -> q00 MFMA -> STAGE -> aHi reads -> q10 -> b1 reads
// -> q11 -> q01 -> vmcnt(0)+barrier. No intra-tile barriers: waves skew freely,
// one wave's ds_reads overlap another's MFMAs; setprio biases the MFMA wave.
#define TILE_BODY(CB, NB, kt, DO_STAGE) do { \
    bf16x8 aLo[2][4], aHi[2][4], b0[4], b1[4]; \
    _Pragma("unroll") \
    for (int ks = 0; ks < 4; ++ks) { \
        aLo[0][ks] = *(const bf16x8*)&As[CB][aoff[0] + co[ks]]; \
        aLo[1][ks] = *(const bf16x8*)&As[CB][aoff[1] + co[ks]]; \
        b0[ks]     = *(const bf16x8*)&Bs[CB][boff[0] + co[ks]]; \
    } \
    __builtin_amdgcn_s_setprio(1); \
    _Pragma("unroll") \
    for (int ks = 0; ks < 4; ++ks) { \
        acc[0][0] = __builtin_amdgcn_mfma_f32_32x32x16_bf16(aLo[0][ks], b0[ks], acc[0][0], 0, 0, 0); \
        acc[1][0] = __builtin_amdgcn_mfma_f32_32x32x16_bf16(aLo[1][ks], b0[ks], acc[1][0], 0, 0, 0); \
    } \
    __builtin_amdgcn_s_setprio(0); \
    if (DO_STAGE) STAGE(NB, (kt) + 64); \
    _Pragma("unroll") \
    for (int ks = 0; ks < 4; ++ks) { \
        aHi[0][ks] = *(const bf16x8*)&As[CB][aoff[2] + co[ks]]; \
        aHi[1][ks] = *(const bf16x8*)&As[CB][aoff[3] + co[ks]]; \
    } \
    __builtin_amdgcn_s_setprio(1); \
    _Pragma("unroll") \
    for (int ks = 0; ks < 4; ++ks) { \
        acc[2][0] = __builtin_amdgcn_mfma_f32_32x32x16_bf16(aHi[0][ks], b0[ks], acc[2][0], 0, 0, 0); \
        acc[3][0] = __builtin_amdgcn_mfma_f32_32x32x16_bf16(aHi[1][ks], b0[ks], acc[3][0], 0, 0, 0); \
    } \
    __builtin_amdgcn_s_setprio(0); \
    _Pragma("unroll") \
    for (int ks = 0; ks < 4; ++ks) \
        b1[ks] = *(const bf16x8*)&Bs[CB][boff[1] + co[ks]]; \
    __builtin_amdgcn_s_setprio(1); \
    _Pragma("unroll") \
    for (int ks = 0; ks < 4; ++ks) { \
        acc[2][1] = __builtin_amdgcn_mfma_f32_32x32x16_bf16(aHi[0][ks], b1[ks], acc[2][1], 0, 0, 0); \
        acc[3][1] = __builtin_amdgcn_mfma_f32_32x32x16_bf16(aHi[1][ks], b1[ks], acc[3][1], 0, 0, 0); \
    } \
    _Pragma("unroll") \
    for (int ks = 0; ks < 4; ++ks) { \
        acc[0][1] = __builtin_amdgcn_mfma_f32_32x32x16_bf16(aLo[0][ks], b1[ks], acc[0][1], 0, 0, 0); \
        acc[1][1] = __builtin_amdgcn_mfma_f32_32x32x16_bf16(aLo[1][ks], b1[ks], acc[1][1], 0, 0, 0); \
    } \
    __builtin_amdgcn_s_setprio(0); \
    asm volatile("s_waitcnt vmcnt(0)\n\ts_barrier" ::: "memory"); \
} while (0)

    // prologue: stage tile 0 into buf0, drain, sync
    STAGE(0, 0);
    asm volatile("s_waitcnt vmcnt(0)\n\ts_barrier" ::: "memory");

    for (int i = 0; i < 32; ++i) {
        int kt = i * 128;
        // tile 2i: compute buf0, stage tile 2i+1 (k=kt+64) into buf1 (always valid)
        TILE_BODY(0, 1, kt, true);
        // tile 2i+1: compute buf1, stage tile 2i+2 (k=kt+128) into buf0 (skip last)
        TILE_BODY(1, 0, kt + 64, (i < 31));
    }
#undef TILE_BODY
#undef STAGE

    // C/D layout (m74/m101): col = lane&31, row = (reg&3) + 8*(reg>>2) + 4*(lane>>5)
    #pragma unroll
    for (int nf = 0; nf < 2; ++nf) {
        float bv = bias[n0 + wn * 64 + nf * 32 + col];
        #pragma unroll
        for (int mf = 0; mf < 4; ++mf) {
            #pragma unroll
            for (int r = 0; r < 16; ++r) {
                int row = m0 + wm * 128 + mf * 32 + (r & 3) + 8 * (r >> 2) + 4 * hi;
                C[(size_t)row * 4096 + n0 + wn * 64 + nf * 32 + col] = acc[mf][nf][r] + bv;
            }
        }
    }
}

extern "C" void kernel_launch(void* const* d_in, const int* in_sizes, int n_in,
                              void* d_out, int out_size, void* d_ws, size_t ws_size,
                              hipStream_t stream) {
    const float* x   = (const float*)d_in[0];   // [4,2048,4096]
    const float* Wb  = (const float*)d_in[1];   // [4096,4096]
    const float* bb  = (const float*)d_in[2];   // [4096]
    const float* e0  = (const float*)d_in[3];   // [32,4096]
    const float* e1  = (const float*)d_in[4];   // [8,4096]
    const float* c0  = (const float*)d_in[5];   // [3,4096,32]
    const float* c1  = (const float*)d_in[6];   // [3,4096,8]
    const int*   m0  = (const int*)d_in[7];     // [3,4096,32] bool->int32
    const int*   m1  = (const int*)d_in[8];     // [3,4096,8]
    float* out = (float*)d_out;                 // [4,2048,4096]

    char* ws = (char*)d_ws;
    unsigned short* xb  = (unsigned short*)ws;              // 67108864 B
    float* Wc           = (float*)(ws + 67108864);          // 655360 B
    float* G            = (float*)(ws + 67764224);          // 655360 B
    unsigned short* Wcb = (unsigned short*)(ws + 68419584); // 33554432 B

    k_prep <<<17024, 256, 0, stream>>>(c0, c1, m0, m1, Wc, x, xb);
    k_gmat <<<512, 256, 0, stream>>>(Wc, G);
    k_wcomb<<<dim3(16, 128), 256, 0, stream>>>(Wb, e0, e1, G, Wcb);
    k_gemm <<<512, 512, 0, stream>>>(xb, Wcb, bb, out);
}

// Round 3
// 613.668 us; speedup vs baseline: 1.1194x; 1.0186x over previous
//
#include <hip/hip_runtime.h>

typedef __attribute__((ext_vector_type(2))) float f32x2;
typedef __attribute__((ext_vector_type(4))) float f32x4;
typedef __attribute__((ext_vector_type(16))) float f32x16;
typedef __attribute__((ext_vector_type(8))) short bf16x8;
typedef __attribute__((ext_vector_type(8))) unsigned short u16x8;

#define GL2LDS(g, l) __builtin_amdgcn_global_load_lds( \
    (const __attribute__((address_space(1))) void*)(g), \
    (__attribute__((address_space(3))) void*)(l), 16, 0, 0)

__device__ __forceinline__ unsigned short f2bf(float x) {
    union { float f; unsigned u; } v; v.f = x;
    unsigned r = (v.u + 0x7FFF + ((v.u >> 16) & 1)) >> 16;
    return (unsigned short)r;
}

// ---------------- Kernel 1 (fused): blocks [0,640): Wc masked expert-sum;
// blocks [640, 17024): x fp32 -> bf16 conversion. The two are independent.
__global__ __launch_bounds__(256) void k_prep(const float* __restrict__ c0,
                                              const float* __restrict__ c1,
                                              const int* __restrict__ m0,
                                              const int* __restrict__ m1,
                                              float* __restrict__ Wc,
                                              const float* __restrict__ x,
                                              unsigned short* __restrict__ xb) {
    int b = blockIdx.x;
    if (b < 640) {
        int idx = b * 256 + threadIdx.x;
        if (idx >= 4096 * 40) return;
        int o = idx / 40, c = idx % 40;
        float s = 0.f;
        if (c < 32) {
            #pragma unroll
            for (int e = 0; e < 3; ++e) {
                int i = (e * 4096 + o) * 32 + c;
                s += c0[i] * (m0[i] != 0 ? 1.f : 0.f);
            }
        } else {
            int r = c - 32;
            #pragma unroll
            for (int e = 0; e < 3; ++e) {
                int i = (e * 4096 + o) * 8 + r;
                s += c1[i] * (m1[i] != 0 ? 1.f : 0.f);
            }
        }
        Wc[idx] = s;
    } else {
        int idx = (b - 640) * 256 + threadIdx.x;  // one per 8 elements; 4194304 total
        f32x4 f0 = ((const f32x4*)x)[(size_t)idx * 2];
        f32x4 f1 = ((const f32x4*)x)[(size_t)idx * 2 + 1];
        u16x8 o;
        o[0] = f2bf(f0[0]); o[1] = f2bf(f0[1]); o[2] = f2bf(f0[2]); o[3] = f2bf(f0[3]);
        o[4] = f2bf(f1[0]); o[5] = f2bf(f1[1]); o[6] = f2bf(f1[2]); o[7] = f2bf(f1[3]);
        *(u16x8*)(xb + (size_t)idx * 8) = o;
    }
}

// ---------------- Kernel 2: G[t][40] = 0.5 * (F @ Wc)[t][:]
__global__ __launch_bounds__(256) void k_gmat(const float* __restrict__ Wc,
                                              float* __restrict__ G) {
    __shared__ float lds[10752];  // staging: 128 f-rows x 84 floats; reused for reduction
    int tid = threadIdx.x;
    int t_base = blockIdx.x * 8;
    int f_slot = tid & 31;
    int tg = (tid >> 5) & 1;
    int rg = tid >> 6;
    float acc[4][10];
    #pragma unroll
    for (int a = 0; a < 4; ++a)
        #pragma unroll
        for (int b = 0; b < 10; ++b) acc[a][b] = 0.f;

    for (int ch = 0; ch < 16; ++ch) {
        __syncthreads();
        // stage 128 f-rows: row f_local <- Wc[(2f-1)*40 .. +80) (cos row || sin row)
        #pragma unroll
        for (int j = 0; j < 10; ++j) {
            int idx = tid + j * 256;        // 0..2559 float4 slots
            int row = idx / 20;
            int v = idx % 20;
            int f = ch * 128 + row;
            f32x4 val = {0.f, 0.f, 0.f, 0.f};
            if (f >= 1) val = *(const f32x4*)(Wc + (2 * f - 1) * 40 + v * 4);
            *(f32x4*)(lds + row * 84 + v * 4) = val;
        }
        __syncthreads();
        #pragma unroll
        for (int j2 = 0; j2 < 4; ++j2) {
            int f_local = f_slot + 32 * j2;
            int f = ch * 128 + f_local;
            float cs[4], sn[4];
            #pragma unroll
            for (int tt = 0; tt < 4; ++tt) {
                int t = t_base + tg * 4 + tt;
                int ph = (f * t) & 4095;                    // exact phase mod 2pi
                float rev = (float)ph * (1.0f / 4096.0f);   // revolutions, exact
                cs[tt] = __builtin_amdgcn_cosf(rev);        // cos(2*pi*rev)
                sn[tt] = __builtin_amdgcn_sinf(rev);
            }
            const float* Lc = lds + f_local * 84 + rg * 10;
            const float* Ls = Lc + 40;
            #pragma unroll
            for (int rr = 0; rr < 10; ++rr) {
                float wc = Lc[rr], ws = Ls[rr];
                #pragma unroll
                for (int tt = 0; tt < 4; ++tt)
                    acc[tt][rr] += cs[tt] * wc + sn[tt] * ws;
            }
        }
    }
    __syncthreads();
    #pragma unroll
    for (int tt = 0; tt < 4; ++tt)
        #pragma unroll
        for (int rr = 0; rr < 10; ++rr)
            lds[tid * 40 + tt * 10 + rr] = acc[tt][rr];
    __syncthreads();
    for (int oi = tid; oi < 320; oi += 256) {
        int t_local = oi / 40, rc = oi % 40;
        int tg2 = t_local >> 2, tsub = t_local & 3;
        int rg2 = rc / 10, rsub = rc % 10;
        float s = 0.f;
        #pragma unroll
        for (int fs = 0; fs < 32; ++fs)
            s += lds[(fs + tg2 * 32 + rg2 * 64) * 40 + tsub * 10 + rsub];
        int t = t_base + t_local;
        float dc = Wc[rc];
        float ny = Wc[4095 * 40 + rc];
        float sign = (t & 1) ? -1.f : 1.f;
        // y[t] = sqrt(2/n)*pairsum + (c0 + (-1)^t c_{n-1})/sqrt(n);  n=4096; x0.5 SCALING
        float g = 0.5f * (0.0220970869120796f * s + (dc + sign * ny) * (1.0f / 64.0f));
        G[t * 40 + rc] = g;
    }
}

// ---------------- Kernel 3: Wcomb[t][d] (bf16) = W_base[t][d] + sum_k G[t][k]*E[k][d]
__global__ __launch_bounds__(256) void k_wcomb(const float* __restrict__ Wb,
                                               const float* __restrict__ enc0,
                                               const float* __restrict__ enc1,
                                               const float* __restrict__ G,
                                               unsigned short* __restrict__ Wcb) {
    __shared__ float ldsE[40 * 256];
    __shared__ float ldsG[32 * 40];
    int tid = threadIdx.x;
    int d0 = blockIdx.x * 256;
    int t0 = blockIdx.y * 32;
    #pragma unroll
    for (int j = 0; j < 10; ++j) {
        int idx = tid + j * 256;   // float4 slots, 40 rows x 64 slots
        int k = idx / 64, v = idx % 64;
        const float* src = (k < 32) ? (enc0 + (size_t)k * 4096) : (enc1 + (size_t)(k - 32) * 4096);
        *(f32x4*)(ldsE + k * 256 + v * 4) = *(const f32x4*)(src + d0 + v * 4);
    }
    #pragma unroll
    for (int j = 0; j < 5; ++j) {
        int idx = tid + j * 256;   // 0..1279
        ldsG[idx] = G[(size_t)(t0 + idx / 40) * 40 + (idx % 40)];
    }
    __syncthreads();
    int dg = tid & 31, tg = tid >> 5;
    // thread covers d-cols {s*64 + dg*2, +1} for s=0..3, t rows t0+tg*4..+3
    f32x2 a[4][4];  // [s][tt]
    #pragma unroll
    for (int s = 0; s < 4; ++s)
        #pragma unroll
        for (int tt = 0; tt < 4; ++tt) a[s][tt] = (f32x2){0.f, 0.f};
    #pragma unroll 8
    for (int r = 0; r < 40; ++r) {
        f32x2 e[4];
        #pragma unroll
        for (int s = 0; s < 4; ++s)
            e[s] = *(const f32x2*)(ldsE + r * 256 + s * 64 + dg * 2);
        #pragma unroll
        for (int tt = 0; tt < 4; ++tt) {
            float g = ldsG[(tg * 4 + tt) * 40 + r];
            #pragma unroll
            for (int s = 0; s < 4; ++s)
                a[s][tt] += g * e[s];
        }
    }
    #pragma unroll
    for (int tt = 0; tt < 4; ++tt) {
        int t = t0 + tg * 4 + tt;
        #pragma unroll
        for (int s = 0; s < 4; ++s) {
            int d = d0 + s * 64 + dg * 2;
            f32x2 wv = *(const f32x2*)(Wb + (size_t)t * 4096 + d);
            f32x2 rv = a[s][tt] + wv;
            unsigned short lo = f2bf(rv[0]), hi = f2bf(rv[1]);
            *(unsigned*)(Wcb + (size_t)t * 4096 + d) = (unsigned)lo | ((unsigned)hi << 16);
        }
    }
}

// ---------------- Kernel 4: C[8192][4096] = A[8192][4096] @ B[4096][4096]^T + bias
// 256x256 tile, BK=64, 8 waves (2Mx4N), 512 threads, 128 KiB LDS (2x dbuf A+B).
// R3 schedule: per tile, ALL 24 fragment reads issue up-front (compiler emits
// partial lgkmcnt waits -> q00 MFMAs run while aHi/b1 reads drain under them),
// then q00+q10 MFMAs, ONE mid-tile barrier, STAGE tile T+2 into the CURRENT
// buffer (all reads of it are issued+consumed: aLo/aHi/b0 before their MFMAs,
// b1 in flight but >=250cy ahead of the async LDS write landing -- R1-verified
// pattern), then q11+q01 from registers, then vmcnt(8)+barrier: waits only for
// tile T+1's loads issued a FULL TILE (~5000cy) earlier; T+2's 8 loads stay in
// flight across the boundary. No vmcnt(0) in steady state (the R2 per-tile
// latency stall), no final barrier.
// SQ_LDS_BANK_CONFLICT ~= ds_read_count x 4 is a structural 4-way floor of
// 128B-row + linear GL2LDS layouts (32 lanes over 8 column slots) -- not a bug.
__global__ __launch_bounds__(512, 2) void k_gemm(const unsigned short* __restrict__ A,
                                                 const unsigned short* __restrict__ B,
                                                 const float* __restrict__ bias,
                                                 float* __restrict__ C) {
    __shared__ __align__(16) short As[2][256 * 64];   // 64 KiB
    __shared__ __align__(16) short Bs[2][256 * 64];   // 64 KiB
    const int tid = threadIdx.x;
    const int lane = tid & 63, w = tid >> 6;
    const int wm = w >> 2, wn = w & 3;          // 2 M-waves x 4 N-waves
    const int col = lane & 31, hi = lane >> 5;  // MFMA fragment lane decomposition
    const int sw = col & 7;                     // swizzle key (== row&7 for frag rows)

    // XCD-aware bijective swizzle: 512 blocks, 512 % 8 == 0
    int bid = blockIdx.x;
    int swz = (bid & 7) * 64 + (bid >> 3);
    int m0 = (swz >> 4) * 256;                  // 32 M-tiles
    int n0 = (swz & 15) * 256;                  // 16 N-tiles

    // staging geometry: one GL2LDS(512 threads) = 64 rows x 64 cols (8 KiB)
    const int srow = w * 8 + (lane >> 3);
    const int scg  = (lane & 7) ^ ((lane >> 3) & 7);
    const unsigned short* Ag = A + (size_t)(m0 + srow) * 4096 + scg * 8;
    const unsigned short* Bg = B + (size_t)(n0 + srow) * 4096 + scg * 8;

#define STAGE(buf, kt) do { \
    _Pragma("unroll") \
    for (int c = 0; c < 4; ++c) { \
        GL2LDS(Ag + (size_t)(c * 64) * 4096 + (kt), &As[buf][(c * 64 + w * 8) * 64]); \
        GL2LDS(Bg + (size_t)(c * 64) * 4096 + (kt), &Bs[buf][(c * 64 + w * 8) * 64]); \
    } \
} while (0)

    // fragment read offsets (shorts)
    int aoff[4], boff[2], co[4];
    #pragma unroll
    for (int mf = 0; mf < 4; ++mf) aoff[mf] = (wm * 128 + mf * 32 + col) * 64;
    #pragma unroll
    for (int nf = 0; nf < 2; ++nf) boff[nf] = (wn * 64 + nf * 32 + col) * 64;
    #pragma unroll
    for (int ks = 0; ks < 4; ++ks) co[ks] = ((ks * 2 + hi) ^ sw) * 8;

    f32x16 acc[4][2];
    #pragma unroll
    for (int mf = 0; mf < 4; ++mf)
        #pragma unroll
        for (int nf = 0; nf < 2; ++nf)
            #pragma unroll
            for (int r = 0; r < 16; ++r) acc[mf][nf][r] = 0.f;

// One K-tile on buffer CB. Stages tile T+2 (k = kt+128) into CB (same parity).
// WAITK: 8 = steady boundary, 0 = final drain, -1 = none (last tile).
#define TILE_BODY(CB, kt, DO_STAGE, WAITK) do { \
    bf16x8 aLo[2][4], aHi[2][4], b0[4], b1[4]; \
    _Pragma("unroll") \
    for (int ks = 0; ks < 4; ++ks) { \
        aLo[0][ks] = *(const bf16x8*)&As[CB][aoff[0] + co[ks]]; \
        aLo[1][ks] = *(const bf16x8*)&As[CB][aoff[1] + co[ks]]; \
        b0[ks]     = *(const bf16x8*)&Bs[CB][boff[0] + co[ks]]; \
    } \
    _Pragma("unroll") \
    for (int ks = 0; ks < 4; ++ks) { \
        aHi[0][ks] = *(const bf16x8*)&As[CB][aoff[2] + co[ks]]; \
        aHi[1][ks] = *(const bf16x8*)&As[CB][aoff[3] + co[ks]]; \
    } \
    _Pragma("unroll") \
    for (int ks = 0; ks < 4; ++ks) \
        b1[ks] = *(const bf16x8*)&Bs[CB][boff[1] + co[ks]]; \
    __builtin_amdgcn_s_setprio(1); \
    _Pragma("unroll") \
    for (int ks = 0; ks < 4; ++ks) { \
        acc[0][0] = __builtin_amdgcn_mfma_f32_32x32x16_bf16(aLo[0][ks], b0[ks], acc[0][0], 0, 0, 0); \
        acc[1][0] = __builtin_amdgcn_mfma_f32_32x32x16_bf16(aLo[1][ks], b0[ks], acc[1][0], 0, 0, 0); \
    } \
    _Pragma("unroll") \
    for (int ks = 0; ks < 4; ++ks) { \
        acc[2][0] = __builtin_amdgcn_mfma_f32_32x32x16_bf16(aHi[0][ks], b0[ks], acc[2][0], 0, 0, 0); \
        acc[3][0] = __builtin_amdgcn_mfma_f32_32x32x16_bf16(aHi[1][ks], b0[ks], acc[3][0], 0, 0, 0); \
    } \
    __builtin_amdgcn_s_setprio(0); \
    asm volatile("s_barrier" ::: "memory"); \
    if (DO_STAGE) STAGE(CB, (kt) + 128); \
    __builtin_amdgcn_s_setprio(1); \
    _Pragma("unroll") \
    for (int ks = 0; ks < 4; ++ks) { \
        acc[2][1] = __builtin_amdgcn_mfma_f32_32x32x16_bf16(aHi[0][ks], b1[ks], acc[2][1], 0, 0, 0); \
        acc[3][1] = __builtin_amdgcn_mfma_f32_32x32x16_bf16(aHi[1][ks], b1[ks], acc[3][1], 0, 0, 0); \
    } \
    _Pragma("unroll") \
    for (int ks = 0; ks < 4; ++ks) { \
        acc[0][1] = __builtin_amdgcn_mfma_f32_32x32x16_bf16(aLo[0][ks], b1[ks], acc[0][1], 0, 0, 0); \
        acc[1][1] = __builtin_amdgcn_mfma_f32_32x32x16_bf16(aLo[1][ks], b1[ks], acc[1][1], 0, 0, 0); \
    } \
    __builtin_amdgcn_s_setprio(0); \
    if ((WAITK) == 8) { \
        asm volatile("s_waitcnt vmcnt(8)\n\ts_barrier" ::: "memory"); \
    } else if ((WAITK) == 0) { \
        asm volatile("s_waitcnt vmcnt(0)\n\ts_barrier" ::: "memory"); \
    } \
} while (0)

    // prologue: stage tiles 0 and 1; vmcnt(8) -> tile0 ready, tile1 in flight
    STAGE(0, 0);
    STAGE(1, 64);
    asm volatile("s_waitcnt vmcnt(8)\n\ts_barrier" ::: "memory");

    for (int i = 0; i < 31; ++i) {
        int kt = i * 128;
        TILE_BODY(0, kt, true, 8);        // tile 2i:   stage 2i+2 -> buf0
        TILE_BODY(1, kt + 64, true, 8);   // tile 2i+1: stage 2i+3 -> buf1
    }
    TILE_BODY(0, 62 * 64, false, 0);      // tile 62: drain (tile 63's loads)
    TILE_BODY(1, 63 * 64, false, -1);     // tile 63: no wait needed
#undef TILE_BODY
#undef STAGE

    // C/D layout (m74/m101): col = lane&31, row = (reg&3) + 8*(reg>>2) + 4*(lane>>5)
    #pragma unroll
    for (int nf = 0; nf < 2; ++nf) {
        float bv = bias[n0 + wn * 64 + nf * 32 + col];
        #pragma unroll
        for (int mf = 0; mf < 4; ++mf) {
            #pragma unroll
            for (int r = 0; r < 16; ++r) {
                int row = m0 + wm * 128 + mf * 32 + (r & 3) + 8 * (r >> 2) + 4 * hi;
                C[(size_t)row * 4096 + n0 + wn * 64 + nf * 32 + col] = acc[mf][nf][r] + bv;
            }
        }
    }
}

extern "C" void kernel_launch(void* const* d_in, const int* in_sizes, int n_in,
                              void* d_out, int out_size, void* d_ws, size_t ws_size,
                              hipStream_t stream) {
    const float* x   = (const float*)d_in[0];   // [4,2048,4096]
    const float* Wb  = (const float*)d_in[1];   // [4096,4096]
    const float* bb  = (const float*)d_in[2];   // [4096]
    const float* e0  = (const float*)d_in[3];   // [32,4096]
    const float* e1  = (const float*)d_in[4];   // [8,4096]
    const float* c0  = (const float*)d_in[5];   // [3,4096,32]
    const float* c1  = (const float*)d_in[6];   // [3,4096,8]
    const int*   m0  = (const int*)d_in[7];     // [3,4096,32] bool->int32
    const int*   m1  = (const int*)d_in[8];     // [3,4096,8]
    float* out = (float*)d_out;                 // [4,2048,4096]

    char* ws = (char*)d_ws;
    unsigned short* xb  = (unsigned short*)ws;              // 67108864 B
    float* Wc           = (float*)(ws + 67108864);          // 655360 B
    float* G            = (float*)(ws + 67764224);          // 655360 B
    unsigned short* Wcb = (unsigned short*)(ws + 68419584); // 33554432 B

    k_prep <<<17024, 256, 0, stream>>>(c0, c1, m0, m1, Wc, x, xb);
    k_gmat <<<512, 256, 0, stream>>>(Wc, G);
    k_wcomb<<<dim3(16, 128), 256, 0, stream>>>(Wb, e0, e1, G, Wcb);
    k_gemm <<<512, 512, 0, stream>>>(xb, Wcb, bb, out);
}

// Round 4
// 592.681 us; speedup vs baseline: 1.1590x; 1.0354x over previous
//
#include <hip/hip_runtime.h>

typedef __attribute__((ext_vector_type(2))) float f32x2;
typedef __attribute__((ext_vector_type(4))) float f32x4;
typedef __attribute__((ext_vector_type(16))) float f32x16;
typedef __attribute__((ext_vector_type(8))) short bf16x8;
typedef __attribute__((ext_vector_type(8))) unsigned short u16x8;

#define GL2LDS(g, l) __builtin_amdgcn_global_load_lds( \
    (const __attribute__((address_space(1))) void*)(g), \
    (__attribute__((address_space(3))) void*)(l), 16, 0, 0)

__device__ __forceinline__ unsigned short f2bf(float x) {
    union { float f; unsigned u; } v; v.f = x;
    unsigned r = (v.u + 0x7FFF + ((v.u >> 16) & 1)) >> 16;
    return (unsigned short)r;
}

// ---------------- Kernel 1 (fused): blocks [0,640): Wc masked expert-sum;
// blocks [640, 17024): x fp32 -> bf16 conversion. The two are independent.
__global__ __launch_bounds__(256) void k_prep(const float* __restrict__ c0,
                                              const float* __restrict__ c1,
                                              const int* __restrict__ m0,
                                              const int* __restrict__ m1,
                                              float* __restrict__ Wc,
                                              const float* __restrict__ x,
                                              unsigned short* __restrict__ xb) {
    int b = blockIdx.x;
    if (b < 640) {
        int idx = b * 256 + threadIdx.x;
        if (idx >= 4096 * 40) return;
        int o = idx / 40, c = idx % 40;
        float s = 0.f;
        if (c < 32) {
            #pragma unroll
            for (int e = 0; e < 3; ++e) {
                int i = (e * 4096 + o) * 32 + c;
                s += c0[i] * (m0[i] != 0 ? 1.f : 0.f);
            }
        } else {
            int r = c - 32;
            #pragma unroll
            for (int e = 0; e < 3; ++e) {
                int i = (e * 4096 + o) * 8 + r;
                s += c1[i] * (m1[i] != 0 ? 1.f : 0.f);
            }
        }
        Wc[idx] = s;
    } else {
        int idx = (b - 640) * 256 + threadIdx.x;  // one per 8 elements; 4194304 total
        f32x4 f0 = ((const f32x4*)x)[(size_t)idx * 2];
        f32x4 f1 = ((const f32x4*)x)[(size_t)idx * 2 + 1];
        u16x8 o;
        o[0] = f2bf(f0[0]); o[1] = f2bf(f0[1]); o[2] = f2bf(f0[2]); o[3] = f2bf(f0[3]);
        o[4] = f2bf(f1[0]); o[5] = f2bf(f1[1]); o[6] = f2bf(f1[2]); o[7] = f2bf(f1[3]);
        *(u16x8*)(xb + (size_t)idx * 8) = o;
    }
}

// ---------------- Kernel 2: G[t][40] = 0.5 * (F @ Wc)[t][:]
__global__ __launch_bounds__(256) void k_gmat(const float* __restrict__ Wc,
                                              float* __restrict__ G) {
    __shared__ float lds[10752];  // staging: 128 f-rows x 84 floats; reused for reduction
    int tid = threadIdx.x;
    int t_base = blockIdx.x * 8;
    int f_slot = tid & 31;
    int tg = (tid >> 5) & 1;
    int rg = tid >> 6;
    float acc[4][10];
    #pragma unroll
    for (int a = 0; a < 4; ++a)
        #pragma unroll
        for (int b = 0; b < 10; ++b) acc[a][b] = 0.f;

    for (int ch = 0; ch < 16; ++ch) {
        __syncthreads();
        // stage 128 f-rows: row f_local <- Wc[(2f-1)*40 .. +80) (cos row || sin row)
        #pragma unroll
        for (int j = 0; j < 10; ++j) {
            int idx = tid + j * 256;        // 0..2559 float4 slots
            int row = idx / 20;
            int v = idx % 20;
            int f = ch * 128 + row;
            f32x4 val = {0.f, 0.f, 0.f, 0.f};
            if (f >= 1) val = *(const f32x4*)(Wc + (2 * f - 1) * 40 + v * 4);
            *(f32x4*)(lds + row * 84 + v * 4) = val;
        }
        __syncthreads();
        #pragma unroll
        for (int j2 = 0; j2 < 4; ++j2) {
            int f_local = f_slot + 32 * j2;
            int f = ch * 128 + f_local;
            float cs[4], sn[4];
            #pragma unroll
            for (int tt = 0; tt < 4; ++tt) {
                int t = t_base + tg * 4 + tt;
                int ph = (f * t) & 4095;                    // exact phase mod 2pi
                float rev = (float)ph * (1.0f / 4096.0f);   // revolutions, exact
                cs[tt] = __builtin_amdgcn_cosf(rev);        // cos(2*pi*rev)
                sn[tt] = __builtin_amdgcn_sinf(rev);
            }
            const float* Lc = lds + f_local * 84 + rg * 10;
            const float* Ls = Lc + 40;
            #pragma unroll
            for (int rr = 0; rr < 10; ++rr) {
                float wc = Lc[rr], ws = Ls[rr];
                #pragma unroll
                for (int tt = 0; tt < 4; ++tt)
                    acc[tt][rr] += cs[tt] * wc + sn[tt] * ws;
            }
        }
    }
    __syncthreads();
    #pragma unroll
    for (int tt = 0; tt < 4; ++tt)
        #pragma unroll
        for (int rr = 0; rr < 10; ++rr)
            lds[tid * 40 + tt * 10 + rr] = acc[tt][rr];
    __syncthreads();
    for (int oi = tid; oi < 320; oi += 256) {
        int t_local = oi / 40, rc = oi % 40;
        int tg2 = t_local >> 2, tsub = t_local & 3;
        int rg2 = rc / 10, rsub = rc % 10;
        float s = 0.f;
        #pragma unroll
        for (int fs = 0; fs < 32; ++fs)
            s += lds[(fs + tg2 * 32 + rg2 * 64) * 40 + tsub * 10 + rsub];
        int t = t_base + t_local;
        float dc = Wc[rc];
        float ny = Wc[4095 * 40 + rc];
        float sign = (t & 1) ? -1.f : 1.f;
        // y[t] = sqrt(2/n)*pairsum + (c0 + (-1)^t c_{n-1})/sqrt(n);  n=4096; x0.5 SCALING
        float g = 0.5f * (0.0220970869120796f * s + (dc + sign * ny) * (1.0f / 64.0f));
        G[t * 40 + rc] = g;
    }
}

// ---------------- Kernel 3: Wcomb[t][d] (bf16) = W_base[t][d] + sum_k G[t][k]*E[k][d]
__global__ __launch_bounds__(256) void k_wcomb(const float* __restrict__ Wb,
                                               const float* __restrict__ enc0,
                                               const float* __restrict__ enc1,
                                               const float* __restrict__ G,
                                               unsigned short* __restrict__ Wcb) {
    __shared__ float ldsE[40 * 256];
    __shared__ float ldsG[32 * 40];
    int tid = threadIdx.x;
    int d0 = blockIdx.x * 256;
    int t0 = blockIdx.y * 32;
    #pragma unroll
    for (int j = 0; j < 10; ++j) {
        int idx = tid + j * 256;   // float4 slots, 40 rows x 64 slots
        int k = idx / 64, v = idx % 64;
        const float* src = (k < 32) ? (enc0 + (size_t)k * 4096) : (enc1 + (size_t)(k - 32) * 4096);
        *(f32x4*)(ldsE + k * 256 + v * 4) = *(const f32x4*)(src + d0 + v * 4);
    }
    #pragma unroll
    for (int j = 0; j < 5; ++j) {
        int idx = tid + j * 256;   // 0..1279
        ldsG[idx] = G[(size_t)(t0 + idx / 40) * 40 + (idx % 40)];
    }
    __syncthreads();
    int dg = tid & 31, tg = tid >> 5;
    // thread covers d-cols {s*64 + dg*2, +1} for s=0..3, t rows t0+tg*4..+3
    f32x2 a[4][4];  // [s][tt]
    #pragma unroll
    for (int s = 0; s < 4; ++s)
        #pragma unroll
        for (int tt = 0; tt < 4; ++tt) a[s][tt] = (f32x2){0.f, 0.f};
    #pragma unroll 8
    for (int r = 0; r < 40; ++r) {
        f32x2 e[4];
        #pragma unroll
        for (int s = 0; s < 4; ++s)
            e[s] = *(const f32x2*)(ldsE + r * 256 + s * 64 + dg * 2);
        #pragma unroll
        for (int tt = 0; tt < 4; ++tt) {
            float g = ldsG[(tg * 4 + tt) * 40 + r];
            #pragma unroll
            for (int s = 0; s < 4; ++s)
                a[s][tt] += g * e[s];
        }
    }
    #pragma unroll
    for (int tt = 0; tt < 4; ++tt) {
        int t = t0 + tg * 4 + tt;
        #pragma unroll
        for (int s = 0; s < 4; ++s) {
            int d = d0 + s * 64 + dg * 2;
            f32x2 wv = *(const f32x2*)(Wb + (size_t)t * 4096 + d);
            f32x2 rv = a[s][tt] + wv;
            unsigned short lo = f2bf(rv[0]), hi = f2bf(rv[1]);
            *(unsigned*)(Wcb + (size_t)t * 4096 + d) = (unsigned)lo | ((unsigned)hi << 16);
        }
    }
}

// ---------------- Kernel 4: C[8192][4096] = A[8192][4096] @ B[4096][4096]^T + bias
// 256x256 tile, BK=64, 8 waves (2Mx4N), 512 threads, 128 KiB LDS (2x dbuf A+B).
// R4: switch fragment geometry to mfma_f32_16x16x32_bf16. R0-R3 all plateaued at
// 36-41% MfmaUtil with SQ_LDS_BANK_CONFLICT == ds_read_count x 4 exactly: the
// 32x32 fragment read (32 lanes x 32 distinct 128B rows, one 16B slot) has a
// structural 4-way conflict floor (XOR swizzle period = 8 rows < 32 rows).
// 16x16x32 fragments read 16 rows x 4 k-chunks: 8 XOR-distinct slots x 2-way
// (free, m136) -> each b128 is bank-uniform (8 words/bank in 8 cy = peak).
// Same read count (24 b128/wave/tile), same bytes, same register budget.
// Sync shape unchanged from R3 (passed): reads up-front -> 32 MFMA (B-lo half)
// -> barrier -> STAGE T+2 into current buf -> 32 MFMA (B-hi half) ->
// vmcnt(8)+barrier (waits tile T+1's loads, issued a full tile earlier).
__global__ __launch_bounds__(512, 2) void k_gemm(const unsigned short* __restrict__ A,
                                                 const unsigned short* __restrict__ B,
                                                 const float* __restrict__ bias,
                                                 float* __restrict__ C) {
    __shared__ __align__(16) short As[2][256 * 64];   // 64 KiB
    __shared__ __align__(16) short Bs[2][256 * 64];   // 64 KiB
    const int tid = threadIdx.x;
    const int lane = tid & 63, w = tid >> 6;
    const int wm = w >> 2, wn = w & 3;          // 2 M-waves x 4 N-waves
    const int l15 = lane & 15;                  // 16x16 fragment row-within-tile
    const int kc = lane >> 4;                   // k-chunk selector 0..3 (8 elems each)
    const int sk = lane & 7;                    // XOR key (== row&7: tile bases are 16-mult)

    // XCD-aware bijective swizzle: 512 blocks, 512 % 8 == 0
    int bid = blockIdx.x;
    int swz = (bid & 7) * 64 + (bid >> 3);
    int m0 = (swz >> 4) * 256;                  // 32 M-tiles
    int n0 = (swz & 15) * 256;                  // 16 N-tiles

    // staging geometry: one GL2LDS(512 threads) = 64 rows x 64 cols (8 KiB)
    // LDS slot (row, c) holds global (row, c ^ (row&7)) via pre-swizzled source.
    const int srow = w * 8 + (lane >> 3);
    const int scg  = (lane & 7) ^ ((lane >> 3) & 7);
    const unsigned short* Ag = A + (size_t)(m0 + srow) * 4096 + scg * 8;
    const unsigned short* Bg = B + (size_t)(n0 + srow) * 4096 + scg * 8;

#define STAGE(buf, kt) do { \
    _Pragma("unroll") \
    for (int c = 0; c < 4; ++c) { \
        GL2LDS(Ag + (size_t)(c * 64) * 4096 + (kt), &As[buf][(c * 64 + w * 8) * 64]); \
        GL2LDS(Bg + (size_t)(c * 64) * 4096 + (kt), &Bs[buf][(c * 64 + w * 8) * 64]); \
    } \
} while (0)

    // fragment read offsets (shorts): A m-tile mt rows wm*128+mt*16+l15;
    // B n-tile nt rows wn*64+nt*16+l15; k-half kh slot = ((kh*4+kc)^sk)*8
    int aoff[8], boff[4];
    #pragma unroll
    for (int mt = 0; mt < 8; ++mt) aoff[mt] = (wm * 128 + mt * 16 + l15) * 64;
    #pragma unroll
    for (int nt = 0; nt < 4; ++nt) boff[nt] = (wn * 64 + nt * 16 + l15) * 64;
    const int s0 = ((0 + kc) ^ sk) * 8;
    const int s1 = ((4 + kc) ^ sk) * 8;

    f32x4 acc[8][4];
    #pragma unroll
    for (int mt = 0; mt < 8; ++mt)
        #pragma unroll
        for (int nt = 0; nt < 4; ++nt)
            #pragma unroll
            for (int r = 0; r < 4; ++r) acc[mt][nt][r] = 0.f;

// One K-tile on buffer CB. Stages tile T+2 (k = kt+128) into CB (same parity).
// WAITK: 8 = steady boundary, 0 = final drain, -1 = none (last tile).
#define TILE_BODY(CB, kt, DO_STAGE, WAITK) do { \
    bf16x8 aF[8][2], bF[4][2]; \
    _Pragma("unroll") \
    for (int mt = 0; mt < 8; ++mt) { \
        aF[mt][0] = *(const bf16x8*)&As[CB][aoff[mt] + s0]; \
        aF[mt][1] = *(const bf16x8*)&As[CB][aoff[mt] + s1]; \
    } \
    _Pragma("unroll") \
    for (int nt = 0; nt < 4; ++nt) { \
        bF[nt][0] = *(const bf16x8*)&Bs[CB][boff[nt] + s0]; \
        bF[nt][1] = *(const bf16x8*)&Bs[CB][boff[nt] + s1]; \
    } \
    __builtin_amdgcn_s_setprio(1); \
    _Pragma("unroll") \
    for (int kh = 0; kh < 2; ++kh) \
        _Pragma("unroll") \
        for (int mt = 0; mt < 8; ++mt) \
            _Pragma("unroll") \
            for (int nt = 0; nt < 2; ++nt) \
                acc[mt][nt] = __builtin_amdgcn_mfma_f32_16x16x32_bf16(aF[mt][kh], bF[nt][kh], acc[mt][nt], 0, 0, 0); \
    __builtin_amdgcn_s_setprio(0); \
    asm volatile("s_barrier" ::: "memory"); \
    if (DO_STAGE) STAGE(CB, (kt) + 128); \
    __builtin_amdgcn_s_setprio(1); \
    _Pragma("unroll") \
    for (int kh = 0; kh < 2; ++kh) \
        _Pragma("unroll") \
        for (int mt = 0; mt < 8; ++mt) \
            _Pragma("unroll") \
            for (int nt = 2; nt < 4; ++nt) \
                acc[mt][nt] = __builtin_amdgcn_mfma_f32_16x16x32_bf16(aF[mt][kh], bF[nt][kh], acc[mt][nt], 0, 0, 0); \
    __builtin_amdgcn_s_setprio(0); \
    if ((WAITK) == 8) { \
        asm volatile("s_waitcnt vmcnt(8)\n\ts_barrier" ::: "memory"); \
    } else if ((WAITK) == 0) { \
        asm volatile("s_waitcnt vmcnt(0)\n\ts_barrier" ::: "memory"); \
    } \
} while (0)

    // prologue: stage tiles 0 and 1; vmcnt(8) -> tile0 ready, tile1 in flight
    STAGE(0, 0);
    STAGE(1, 64);
    asm volatile("s_waitcnt vmcnt(8)\n\ts_barrier" ::: "memory");

    for (int i = 0; i < 31; ++i) {
        int kt = i * 128;
        TILE_BODY(0, kt, true, 8);        // tile 2i:   stage 2i+2 -> buf0
        TILE_BODY(1, kt + 64, true, 8);   // tile 2i+1: stage 2i+3 -> buf1
    }
    TILE_BODY(0, 62 * 64, false, 0);      // tile 62: drain (tile 63's loads)
    TILE_BODY(1, 63 * 64, false, -1);     // tile 63: no wait needed
#undef TILE_BODY
#undef STAGE

    // C/D layout 16x16 (m89/m91): col = lane&15, row = (lane>>4)*4 + reg
    const int r4 = (lane >> 4) * 4;
    float bv[4];
    #pragma unroll
    for (int nt = 0; nt < 4; ++nt) bv[nt] = bias[n0 + wn * 64 + nt * 16 + l15];
    #pragma unroll
    for (int mt = 0; mt < 8; ++mt) {
        #pragma unroll
        for (int nt = 0; nt < 4; ++nt) {
            #pragma unroll
            for (int r = 0; r < 4; ++r) {
                int row = m0 + wm * 128 + mt * 16 + r4 + r;
                C[(size_t)row * 4096 + n0 + wn * 64 + nt * 16 + l15] = acc[mt][nt][r] + bv[nt];
            }
        }
    }
}

extern "C" void kernel_launch(void* const* d_in, const int* in_sizes, int n_in,
                              void* d_out, int out_size, void* d_ws, size_t ws_size,
                              hipStream_t stream) {
    const float* x   = (const float*)d_in[0];   // [4,2048,4096]
    const float* Wb  = (const float*)d_in[1];   // [4096,4096]
    const float* bb  = (const float*)d_in[2];   // [4096]
    const float* e0  = (const float*)d_in[3];   // [32,4096]
    const float* e1  = (const float*)d_in[4];   // [8,4096]
    const float* c0  = (const float*)d_in[5];   // [3,4096,32]
    const float* c1  = (const float*)d_in[6];   // [3,4096,8]
    const int*   m0  = (const int*)d_in[7];     // [3,4096,32] bool->int32
    const int*   m1  = (const int*)d_in[8];     // [3,4096,8]
    float* out = (float*)d_out;                 // [4,2048,4096]

    char* ws = (char*)d_ws;
    unsigned short* xb  = (unsigned short*)ws;              // 67108864 B
    float* Wc           = (float*)(ws + 67108864);          // 655360 B
    float* G            = (float*)(ws + 67764224);          // 655360 B
    unsigned short* Wcb = (unsigned short*)(ws + 68419584); // 33554432 B

    k_prep <<<17024, 256, 0, stream>>>(c0, c1, m0, m1, Wc, x, xb);
    k_gmat <<<512, 256, 0, stream>>>(Wc, G);
    k_wcomb<<<dim3(16, 128), 256, 0, stream>>>(Wb, e0, e1, G, Wcb);
    k_gemm <<<512, 512, 0, stream>>>(xb, Wcb, bb, out);
}